// Round 4
// baseline (354.495 us; speedup 1.0000x reference)
//
#include <hip/hip_runtime.h>
#include <stdint.h>

#define BB 8
#define CIN 256
#define NSP 16384      // H*W
#define HID 128

typedef __bf16 bfrag __attribute__((ext_vector_type(8)));
typedef float  f32x4 __attribute__((ext_vector_type(4)));

__device__ __forceinline__ unsigned short f2bf(float f) {
  union { float f; unsigned int u; } v; v.f = f;
  unsigned int u = v.u;
  return (unsigned short)((u + 0x7FFFu + ((u >> 16) & 1u)) >> 16);  // RNE
}

// async global -> LDS, 16B per lane; LDS dest = wave-uniform base + lane*16
#define GLL16(gp, lp)                                                              \
  __builtin_amdgcn_global_load_lds((const __attribute__((address_space(1))) void*)(gp), \
                                   (__attribute__((address_space(3))) void*)(lp), 16, 0, 0)

// ---------------- cast fp32 -> bf16 (for w_qkv k,v rows) ----------------
__global__ __launch_bounds__(256) void la_cast_w(const float* __restrict__ w,
                                                 unsigned short* __restrict__ wb, int n) {
  int i = blockIdx.x * 256 + threadIdx.x;
  if (i < n) wb[i] = f2bf(w[i]);
}

// ---------------- transpose+cast x [B][C][N] f32 -> xT [B][N][C] bf16 ----------------
__global__ __launch_bounds__(256) void la_transpose(const float* __restrict__ x,
                                                    unsigned short* __restrict__ xT) {
  __shared__ __align__(16) float tile[64][68];
  const int n0 = blockIdx.x * 64;
  const int c0 = blockIdx.y * 64;
  const int b  = blockIdx.z;
  const int t = threadIdx.x;
  const float* xp = x + (size_t)b * CIN * NSP;
  const int nseg = (t & 15) * 4;
  const int crow = t >> 4;
#pragma unroll
  for (int i = 0; i < 4; ++i) {
    const int c = crow + i * 16;
    const float4 v = *(const float4*)(xp + (size_t)(c0 + c) * NSP + n0 + nseg);
    tile[nseg + 0][c] = v.x;
    tile[nseg + 1][c] = v.y;
    tile[nseg + 2][c] = v.z;
    tile[nseg + 3][c] = v.w;
  }
  __syncthreads();
  const int n = t >> 2;
  const int seg = (t & 3) * 16;
  unsigned short* op = xT + ((size_t)b * NSP + n0 + n) * CIN + c0 + seg;
  union { unsigned short u[16]; uint4 q[2]; } pk;
#pragma unroll
  for (int k = 0; k < 16; ++k) pk.u[k] = f2bf(tile[n][seg + k]);
  *(uint4*)(op) = pk.q[0];
  *(uint4*)(op + 8) = pk.q[1];
}

// ---------------- k,v GEMM (m97 staging) + exp + row-sums + context ----------------
// Block: (chunk, b) -> 128-n tile. M=256 (k rows 0..127, v rows 128..255 of wqb2).
// 512 threads = 8 waves; wave wv owns m rows {wv*16 (k), 128+wv*16 (v)}; acc[2][8].
__global__ __launch_bounds__(512) void la_kv_ctx(const unsigned short* __restrict__ wkv,
                                                 const unsigned short* __restrict__ xT,
                                                 float* __restrict__ ctxu,
                                                 float* __restrict__ sums) {
  __shared__ __align__(16) union {
    struct { unsigned short Wt[256][32]; unsigned short Xt[128][32]; } g;   // 24576 B
    struct { unsigned short Lk[64][136]; unsigned short Lv[64][136];
             float Pc[4][1024]; } e;                                        // 51200 B
  } sh;
  const int chunk = blockIdx.x;
  const int n0 = chunk * 128;
  const int b = blockIdx.y;
  const int t = threadIdx.x;
  const int lane = t & 63, wv = t >> 6;
  const int l15 = lane & 15, q = lane >> 4;
  const int wbase = (t & 0x1C0) * 16;           // wave-uniform LDS byte base (wv*1024)
  const int grow = t >> 2, gseg = (t & 3) * 8;  // staging unit -> (row, col-seg)
  f32x4 acc[2][8];
#pragma unroll
  for (int i = 0; i < 2; ++i)
#pragma unroll
    for (int j = 0; j < 8; ++j) acc[i][j] = 0.0f;
  const unsigned short* xbase = xT + ((size_t)b * NSP + n0) * CIN;
  for (int kc = 0; kc < 8; ++kc) {
    __syncthreads();
    const int ko = kc * 32 + gseg;
    GLL16(wkv + (size_t)grow * CIN + ko,          (char*)sh.g.Wt + wbase);
    GLL16(wkv + (size_t)(grow + 128) * CIN + ko,  (char*)sh.g.Wt + 8192 + wbase);
    GLL16(xbase + (size_t)grow * CIN + ko,        (char*)sh.g.Xt + wbase);
    __syncthreads();
    bfrag a0 = *(const bfrag*)&sh.g.Wt[wv * 16 + l15][q * 8];
    bfrag a1 = *(const bfrag*)&sh.g.Wt[128 + wv * 16 + l15][q * 8];
    bfrag bb[8];
#pragma unroll
    for (int ni = 0; ni < 8; ++ni) bb[ni] = *(const bfrag*)&sh.g.Xt[ni * 16 + l15][q * 8];
#pragma unroll
    for (int ni = 0; ni < 8; ++ni) {
      acc[0][ni] = __builtin_amdgcn_mfma_f32_16x16x32_bf16(a0, bb[ni], acc[0][ni], 0, 0, 0);
      acc[1][ni] = __builtin_amdgcn_mfma_f32_16x16x32_bf16(a1, bb[ni], acc[1][ni], 0, 0, 0);
    }
  }
  __syncthreads();
  // ---- k row-sums of exp (unnormalized softmax; k~N(0,1), no overflow) ----
  {
    float sp[4] = {0.f, 0.f, 0.f, 0.f};
#pragma unroll
    for (int ni = 0; ni < 8; ++ni)
#pragma unroll
      for (int rg = 0; rg < 4; ++rg) sp[rg] += __expf(acc[0][ni][rg]);
#pragma unroll
    for (int rg = 0; rg < 4; ++rg) {
      float s = sp[rg];
      s += __shfl_down(s, 8, 16);
      s += __shfl_down(s, 4, 16);
      s += __shfl_down(s, 2, 16);
      s += __shfl_down(s, 1, 16);
      if (l15 == 0) atomicAdd(&sums[b * 128 + wv * 16 + q * 4 + rg], s);
    }
  }
  // ---- context in two 64-row phases (heads 2ph, 2ph+1) ----
#pragma unroll
  for (int ph = 0; ph < 2; ++ph) {
    if ((wv >> 2) == ph) {
      const int r = (wv & 3) * 16 + q * 4;
#pragma unroll
      for (int ni = 0; ni < 8; ++ni)
#pragma unroll
        for (int rg = 0; rg < 4; ++rg) {
          sh.e.Lk[r + rg][ni * 16 + l15] = f2bf(__expf(acc[0][ni][rg]));
          sh.e.Lv[r + rg][ni * 16 + l15] = f2bf(acc[1][ni][rg]);
        }
    }
    __syncthreads();
    const int hl = wv >> 2, nq = wv & 3;   // local head, n-quarter (32 n)
    f32x4 c2[2][2];
    c2[0][0] = 0.f; c2[0][1] = 0.f; c2[1][0] = 0.f; c2[1][1] = 0.f;
    bfrag ka[2], vb[2];
#pragma unroll
    for (int d2 = 0; d2 < 2; ++d2)
      ka[d2] = *(const bfrag*)&sh.e.Lk[hl * 32 + d2 * 16 + l15][nq * 32 + q * 8];
#pragma unroll
    for (int e2 = 0; e2 < 2; ++e2)
      vb[e2] = *(const bfrag*)&sh.e.Lv[hl * 32 + e2 * 16 + l15][nq * 32 + q * 8];
#pragma unroll
    for (int d2 = 0; d2 < 2; ++d2)
#pragma unroll
      for (int e2 = 0; e2 < 2; ++e2)
        c2[d2][e2] = __builtin_amdgcn_mfma_f32_16x16x32_bf16(ka[d2], vb[e2], c2[d2][e2], 0, 0, 0);
    const int slot = hl * 2 + (nq & 1);
    if (nq < 2) {
#pragma unroll
      for (int d2 = 0; d2 < 2; ++d2)
#pragma unroll
        for (int e2 = 0; e2 < 2; ++e2)
#pragma unroll
          for (int rg = 0; rg < 4; ++rg)
            sh.e.Pc[slot][(d2 * 16 + q * 4 + rg) * 32 + e2 * 16 + l15] = c2[d2][e2][rg];
    }
    __syncthreads();
    if (nq >= 2) {
#pragma unroll
      for (int d2 = 0; d2 < 2; ++d2)
#pragma unroll
        for (int e2 = 0; e2 < 2; ++e2)
#pragma unroll
          for (int rg = 0; rg < 4; ++rg)
            sh.e.Pc[slot][(d2 * 16 + q * 4 + rg) * 32 + e2 * 16 + l15] += c2[d2][e2][rg];
    }
    __syncthreads();
    for (int idx = t; idx < 2048; idx += 512) {
      const int h2 = idx >> 10, pos = idx & 1023;
      atomicAdd(&ctxu[((size_t)(b * 4 + ph * 2 + h2)) * 1024 + pos],
                sh.e.Pc[h2 * 2][pos] + sh.e.Pc[h2 * 2 + 1][pos]);
    }
    __syncthreads();
  }
}

// ---------------- Wcomb[b][o][c] = sum_c' Weff[b][o][c'] * Wq[c'][c] ----------------
// Weff[b][o][h*32+d] = (1/sums) * sum_e w_out[o][h*32+e] * ctxu[b,h,d,e]
__global__ __launch_bounds__(256) void la_wcomb(const float* __restrict__ w_out,
                                                const float* __restrict__ w_qkv,
                                                const float* __restrict__ ctxu,
                                                const float* __restrict__ sums,
                                                unsigned short* __restrict__ wcomb) {
  __shared__ float Weff_l[128];
  const int o = blockIdx.x;
  const int b = blockIdx.y;
  const int t = threadIdx.x;
  if (t < 128) {
    const int h = t >> 5, d = t & 31;
    const float* wrow = w_out + (size_t)o * HID + h * 32;
    const float* crow = ctxu + ((size_t)(b * 4 + h) * 32 + d) * 32;
    float s = 0.f;
#pragma unroll 8
    for (int e = 0; e < 32; ++e) s += wrow[e] * crow[e];
    Weff_l[t] = s / sums[b * 128 + t];
  }
  __syncthreads();
  float a = 0.f;
#pragma unroll 8
  for (int cp = 0; cp < 128; ++cp) a += Weff_l[cp] * w_qkv[(size_t)cp * CIN + t];
  wcomb[((size_t)b * 256 + o) * 256 + t] = f2bf(a);
}

// ---------------- final GEMM: out[b][o][n] = sum_c Wcomb[b][o][c]*xT[b][n][c] + b_out[o] ----------------
__global__ __launch_bounds__(512) void la_final(const unsigned short* __restrict__ wcomb,
                                                const unsigned short* __restrict__ xT,
                                                const float* __restrict__ b_out,
                                                float* __restrict__ out) {
  __shared__ __align__(16) unsigned short Wt[256][32];   // 16384 B
  __shared__ __align__(16) unsigned short Xt[128][32];   //  8192 B
  const int chunk = blockIdx.x;
  const int n0 = chunk * 128;
  const int b = blockIdx.y;
  const int t = threadIdx.x;
  const int lane = t & 63, wv = t >> 6;
  const int l15 = lane & 15, q = lane >> 4;
  const int wbase = (t & 0x1C0) * 16;
  const int grow = t >> 2, gseg = (t & 3) * 8;
  f32x4 acc[2][8];
#pragma unroll
  for (int i = 0; i < 2; ++i)
#pragma unroll
    for (int j = 0; j < 8; ++j) acc[i][j] = 0.0f;
  const unsigned short* abase = wcomb + (size_t)b * 256 * 256;
  const unsigned short* xbase = xT + ((size_t)b * NSP + n0) * CIN;
  for (int kc = 0; kc < 8; ++kc) {
    __syncthreads();
    const int ko = kc * 32 + gseg;
    GLL16(abase + (size_t)grow * 256 + ko,        (char*)Wt + wbase);
    GLL16(abase + (size_t)(grow + 128) * 256 + ko, (char*)Wt + 8192 + wbase);
    GLL16(xbase + (size_t)grow * CIN + ko,        (char*)Xt + wbase);
    __syncthreads();
    bfrag a0 = *(const bfrag*)&Wt[wv * 16 + l15][q * 8];
    bfrag a1 = *(const bfrag*)&Wt[128 + wv * 16 + l15][q * 8];
    bfrag bb[8];
#pragma unroll
    for (int ni = 0; ni < 8; ++ni) bb[ni] = *(const bfrag*)&Xt[ni * 16 + l15][q * 8];
#pragma unroll
    for (int ni = 0; ni < 8; ++ni) {
      acc[0][ni] = __builtin_amdgcn_mfma_f32_16x16x32_bf16(a0, bb[ni], acc[0][ni], 0, 0, 0);
      acc[1][ni] = __builtin_amdgcn_mfma_f32_16x16x32_bf16(a1, bb[ni], acc[1][ni], 0, 0, 0);
    }
  }
  float* obase = out + (size_t)b * 256 * NSP;
#pragma unroll
  for (int band = 0; band < 2; ++band) {
    const int ob = band * 128 + wv * 16 + q * 4;
    const float4 bias = *(const float4*)(b_out + ob);
    float ba[4] = {bias.x, bias.y, bias.z, bias.w};
#pragma unroll
    for (int ni = 0; ni < 8; ++ni) {
      const int n = n0 + ni * 16 + l15;
#pragma unroll
      for (int rg = 0; rg < 4; ++rg)
        obase[(size_t)(ob + rg) * NSP + n] = acc[band][ni][rg] + ba[rg];
    }
  }
}

// ---------------- workspace layout ----------------
// xT    : 0         , 67108864 B  (B*N*C bf16)
// wqb2  : 67108864  , 131072 B    (k,v rows 128..383 of w_qkv, bf16)
// wcomb : 67239936  , 1048576 B   (B*256*256 bf16)
// ctxu  : 68288512  , 131072 B    (fp32, zeroed each call)
// sums  : 68419584  , 4096 B      (fp32, zeroed each call)
// total ~68.4 MB

extern "C" void kernel_launch(void* const* d_in, const int* in_sizes, int n_in,
                              void* d_out, int out_size, void* d_ws, size_t ws_size,
                              hipStream_t stream) {
  (void)in_sizes; (void)n_in; (void)out_size; (void)ws_size;
  const float* x     = (const float*)d_in[0];
  const float* w_qkv = (const float*)d_in[1];
  const float* w_out = (const float*)d_in[2];
  const float* b_out = (const float*)d_in[3];
  float* out = (float*)d_out;
  char* ws = (char*)d_ws;
  unsigned short* xT    = (unsigned short*)(ws);
  unsigned short* wqb2  = (unsigned short*)(ws + 67108864);
  unsigned short* wcomb = (unsigned short*)(ws + 67239936);
  float* ctxu           = (float*)(ws + 68288512);
  float* sums           = (float*)(ws + 68419584);

  hipMemsetAsync(ctxu, 0, 131072 + 4096, stream);
  la_cast_w<<<dim3(256), dim3(256), 0, stream>>>(w_qkv + 128 * CIN, wqb2, 256 * CIN);
  la_transpose<<<dim3(NSP / 64, CIN / 64, BB), dim3(256), 0, stream>>>(x, xT);
  la_kv_ctx<<<dim3(NSP / 128, BB), dim3(512), 0, stream>>>(wqb2, xT, ctxu, sums);
  la_wcomb<<<dim3(256, BB), dim3(256), 0, stream>>>(w_out, w_qkv, ctxu, sums, wcomb);
  la_final<<<dim3(NSP / 128, BB), dim3(512), 0, stream>>>(wcomb, xT, b_out, out);
}